// Round 9
// baseline (20.068 us; speedup 1.0000x reference)
//
#include <hip/hip_runtime.h>
#include <hip/hip_bf16.h>
#include <hip/hip_fp16.h>

#define TLEN 4096
#define KTAPS 256
#define NT 18       // Toeplitz A tiles (K window = 288 = 18*16)
#define CHUNK 256   // floats of t per chunk
#define NCHK 4      // chunks per strip (strip = 1024 outputs)
#define RING 4      // LDS ring slots (4 x 16 k-chunks = 64 k-chunks)

typedef __attribute__((ext_vector_type(8))) _Float16 f16x8;
typedef __attribute__((ext_vector_type(4))) unsigned int uint4v;
typedef __attribute__((ext_vector_type(16))) float f32x16;

static __device__ __forceinline__ unsigned int pkf16(float a, float b) {
    return __builtin_bit_cast(unsigned int, __builtin_amdgcn_cvt_pkrtz(a, b));
}

// ------------- Persistent chunk-pipelined fused kernel -------------
// Grid: (rows/32)*4 blocks of 512 threads (8 waves), ~1 block/CU. Block covers
// rows [rt*32,+32) x outputs [sg*1024,+1024) as 4 chunks of 256, with a rolling
// 4-slot LDS fragment ring (chunk c needs slots of chunks c-1,c). Steady loop:
// issue loads(c+1) -> MFMA(c) -> store(c) -> convert+ds_write(c+1) -> barrier.
__global__ void __launch_bounds__(512, 2)
frac_conv_pipe(const float* __restrict__ x,
               const float* __restrict__ loc,
               const float* __restrict__ scale,
               const float* __restrict__ eps,
               float* __restrict__ out) {
    __shared__ unsigned int wrevp[320];                            // 1.25 KB
    __shared__ __align__(16) unsigned short Bf[RING * 16 * 64 * 8]; // 64 KB

    const int tid  = threadIdx.x;
    const int wave = tid >> 6;
    const int lane = tid & 63;
    const int l5   = lane >> 5;
    const int ln   = lane & 31;

    // XCD swizzle: xcd = bid&7 (HW round-robin). Give each XCD 8 rts x 4 strips
    // so halo-sharing strip neighbors land in the same XCD's L2.
    int rt, sg;
    if (gridDim.x == 256) {
        const int xcd = blockIdx.x & 7;
        const int k   = blockIdx.x >> 3;       // 0..31
        rt = xcd * 8 + (k >> 2);
        sg = k & 3;
    } else {
        rt = blockIdx.x >> 2;
        sg = blockIdx.x & 3;
    }
    const int S0 = sg * (CHUNK * NCHK);        // strip start (outputs & t)

    const int r  = tid >> 4;                   // row 0..31 (16 threads/row)
    const int cg = tid & 15;
    const float* __restrict__ xrow = x + (size_t)(rt * 32 + r) * TLEN;

    // issue loads of chunk c: t in [S0 + c*256, +256), 4 float4/thread
    auto ISSUE = [&](int c, float4* v) {
        #pragma unroll
        for (int q = 0; q < 4; ++q) {
            const int tg = S0 + c * CHUNK + cg * 4 + q * 64;
            v[q] = (tg >= 0) ? *(const float4*)(xrow + tg)
                             : make_float4(0.f, 0.f, 0.f, 0.f);
        }
    };
    // convert chunk c and write into ring slot (c+1)&3 in MFMA fragment layout
    auto WRITE = [&](int c, const float4* v) {
        const int slot = (c + 1) & (RING - 1);
        uint2* Bf2 = (uint2*)Bf;
        #pragma unroll
        for (int q = 0; q < 4; ++q) {
            const int w0 = cg * 4 + q * 64;            // [0,256)
            const int kc = w0 >> 4;                    // k-chunk in slot, 0..15
            const int h8 = (w0 >> 3) & 1;              // k-half
            const int e0 = w0 & 7;                     // 0 or 4
            const int uoff = ((slot * 16 + kc) * 64 + r + 32 * h8) * 8 + e0;
            Bf2[uoff >> 2] = make_uint2(pkf16(v[q].x, v[q].y),
                                        pkf16(v[q].z, v[q].w));
        }
    };

    // ---- prologue: burst loads of halo chunk (-1) and chunk 0 ----
    float4 v0[4], v1[4];
    ISSUE(-1, v0);
    ISSUE(0, v1);

    // ---- taps: wave 0 shfl cumprod scan -> packed reversed fp16 table ----
    if (wave == 0) {
        const float alpha = loc[0] + log1pf(expf(scale[0])) * eps[0];
        const int j0 = 4 * lane;
        const float f0 = (j0 == 0) ? 1.0f : (((float)j0 - 1.0f - alpha) / (float)j0);
        const float f1 = (((float)j0 + 0.0f - alpha) / (float)(j0 + 1));
        const float f2 = (((float)j0 + 1.0f - alpha) / (float)(j0 + 2));
        const float f3 = (((float)j0 + 2.0f - alpha) / (float)(j0 + 3));
        const float p0 = f0, p1 = p0 * f1, p2 = p1 * f2, p3 = p2 * f3;
        float g = p3;
        #pragma unroll
        for (int dlt = 1; dlt < 64; dlt <<= 1) {
            const float t = __shfl_up(g, dlt, 64);
            if (lane >= dlt) g *= t;
        }
        float Sprev = __shfl_up(g, 1, 64);
        if (lane == 0) Sprev = 1.0f;
        const float q0 = Sprev * p0, q1 = Sprev * p1, q2 = Sprev * p2, q3 = g;
        const float wm1 = (lane == 0) ? 0.0f : Sprev;   // w[4l-1]
        uint4v pk;
        pk[0] = pkf16(q3, q2);
        pk[1] = pkf16(q2, q1);
        pk[2] = pkf16(q1, q0);
        pk[3] = pkf16(q0, wm1);
        *(uint4v*)(wrevp + 284 - 4 * lane) = pk;
        if (lane == 63) wrevp[31] = pkf16(0.0f, q3);
        if (lane < 31)  wrevp[lane] = 0u;
        if (lane < 32)  wrevp[288 + lane] = 0u;
    }

    WRITE(-1, v0);
    WRITE(0, v1);
    __syncthreads();

    // ---- steady loop over 4 chunks ----
    const f16x8* Bv = (const f16x8*)Bf;
    const int o0 = 31 - ln + 8 * l5;              // tap-table base for this lane
    float* __restrict__ orow = out + (size_t)(rt * 32 + ln) * TLEN;

    auto LOADA = [&](int d) -> f16x8 {
        const int o = o0 + 16 * d;
        uint4v u;
        u[0] = wrevp[o];
        u[1] = wrevp[o + 2];
        u[2] = wrevp[o + 4];
        u[3] = wrevp[o + 6];
        return __builtin_bit_cast(f16x8, u);
    };

    #pragma unroll
    for (int c = 0; c < NCHK; ++c) {
        if (c + 1 < NCHK) ISSUE(c + 1, v0);       // in flight across MFMA body

        const int kc0 = 16 * c + 2 * wave;        // ring k-chunk base, mod 64
        auto LDB = [&](int d) -> f16x8 {
            return Bv[((kc0 + d) & 63) * 64 + lane];
        };

        f16x8 Afr[NT];
        f16x8 Bfr[NT];
        Bfr[0] = LDB(0); Bfr[1] = LDB(1); Bfr[2] = LDB(2); Bfr[3] = LDB(3);
        Afr[0] = LOADA(0); Afr[1] = LOADA(1);

        f32x16 acc = {0.f, 0.f, 0.f, 0.f, 0.f, 0.f, 0.f, 0.f,
                      0.f, 0.f, 0.f, 0.f, 0.f, 0.f, 0.f, 0.f};
        #pragma unroll
        for (int d = 0; d < NT; ++d) {
            if (d + 4 < NT) Bfr[d + 4] = LDB(d + 4);
            if (d + 2 < NT) Afr[d + 2] = LOADA(d + 2);
            acc = __builtin_amdgcn_mfma_f32_32x32x16_f16(Afr[d], Bfr[d], acc, 0, 0, 0);
        }

        // store chunk c (D: col=ln, m=(reg&3)+8*(reg>>2)+4*l5)
        const int n0 = S0 + c * CHUNK + wave * 32;
        #pragma unroll
        for (int g = 0; g < 4; ++g) {
            *(float4*)(orow + n0 + 8 * g + 4 * l5) =
                make_float4(acc[4 * g + 0], acc[4 * g + 1], acc[4 * g + 2], acc[4 * g + 3]);
        }

        if (c + 1 < NCHK) {
            WRITE(c + 1, v0);                     // vmcnt wait on loads lands here
            __syncthreads();
        }
    }
}

// ---------------- Fallback path (proven round-1 fp32 kernels) ----------------
__global__ void gl_coeff_kernel(const float* __restrict__ loc,
                                const float* __restrict__ scale,
                                const float* __restrict__ eps,
                                float* __restrict__ w_out) {
    __shared__ float s[KTAPS];
    const int j = threadIdx.x;
    const float alpha = loc[0] + log1pf(expf(scale[0])) * eps[0];
    float f = (j == 0) ? 1.0f : (((float)j - 1.0f - alpha) / (float)j);
    s[j] = f;
    __syncthreads();
    #pragma unroll
    for (int st = 1; st < KTAPS; st <<= 1) {
        float v = s[j];
        float p = (j >= st) ? s[j - st] : 1.0f;
        __syncthreads();
        s[j] = v * p;
        __syncthreads();
    }
    w_out[j] = s[j];
}

__global__ void __launch_bounds__(256)
frac_conv_kernel(const float* __restrict__ x,
                 const float* __restrict__ w,
                 float* __restrict__ out) {
    __shared__ __align__(16) float xs[KTAPS + TLEN];
    __shared__ __align__(16) float wl[KTAPS];
    const int row = blockIdx.x;
    const int tid = threadIdx.x;
    const float* __restrict__ xr = x + (size_t)row * TLEN;
    float* __restrict__ orow = out + (size_t)row * TLEN;
    if (tid < 64) ((float4*)xs)[tid] = make_float4(0.f, 0.f, 0.f, 0.f);
    float4* xs4w = (float4*)(xs + KTAPS);
    const float4* xr4 = (const float4*)xr;
    #pragma unroll
    for (int k = 0; k < 4; ++k) xs4w[tid + k * 256] = xr4[tid + k * 256];
    if (tid < 64) ((float4*)wl)[tid] = ((const float4*)w)[tid];
    __syncthreads();
    const float4* __restrict__ xsv = (const float4*)xs;
    float4 acc[4]; float4 lo[4], hi[4]; int n0[4];
    #pragma unroll
    for (int g = 0; g < 4; ++g) {
        n0[g] = (tid << 2) + (g << 10);
        acc[g] = make_float4(0.f, 0.f, 0.f, 0.f);
        const int c = n0[g] >> 2;
        hi[g] = xsv[64 + c];
        lo[g] = xsv[63 + c];
    }
    #pragma unroll 4
    for (int j = 0; j < KTAPS - 4; j += 4) {
        const float4 w4 = *(const float4*)(wl + j);
        #pragma unroll
        for (int g = 0; g < 4; ++g) {
            acc[g].x += w4.x*hi[g].x + w4.y*lo[g].w + w4.z*lo[g].z + w4.w*lo[g].y;
            acc[g].y += w4.x*hi[g].y + w4.y*hi[g].x + w4.z*lo[g].w + w4.w*lo[g].z;
            acc[g].z += w4.x*hi[g].z + w4.y*hi[g].y + w4.z*hi[g].x + w4.w*lo[g].w;
            acc[g].w += w4.x*hi[g].w + w4.y*hi[g].z + w4.z*hi[g].y + w4.w*hi[g].x;
            hi[g] = lo[g];
            lo[g] = xsv[64 + ((n0[g] - j - 8) >> 2)];
        }
    }
    {
        const float4 w4 = *(const float4*)(wl + (KTAPS - 4));
        #pragma unroll
        for (int g = 0; g < 4; ++g) {
            acc[g].x += w4.x*hi[g].x + w4.y*lo[g].w + w4.z*lo[g].z + w4.w*lo[g].y;
            acc[g].y += w4.x*hi[g].y + w4.y*hi[g].x + w4.z*lo[g].w + w4.w*lo[g].z;
            acc[g].z += w4.x*hi[g].z + w4.y*hi[g].y + w4.z*hi[g].x + w4.w*lo[g].w;
            acc[g].w += w4.x*hi[g].w + w4.y*hi[g].z + w4.z*hi[g].y + w4.w*hi[g].x;
        }
    }
    #pragma unroll
    for (int g = 0; g < 4; ++g) *(float4*)(orow + n0[g]) = acc[g];
}

extern "C" void kernel_launch(void* const* d_in, const int* in_sizes, int n_in,
                              void* d_out, int out_size, void* d_ws, size_t ws_size,
                              hipStream_t stream) {
    const float* x     = (const float*)d_in[0];
    const float* loc   = (const float*)d_in[1];
    const float* scale = (const float*)d_in[2];
    const float* eps   = (const float*)d_in[3];
    float* out = (float*)d_out;
    const int rows = in_sizes[0] / TLEN;  // 2048

    if ((rows % 32) == 0) {
        frac_conv_pipe<<<(rows / 32) * 4, 512, 0, stream>>>(x, loc, scale, eps, out);
    } else {
        float* w = (float*)d_ws;
        gl_coeff_kernel<<<1, 256, 0, stream>>>(loc, scale, eps, w);
        frac_conv_kernel<<<rows, 256, 0, stream>>>(x, w, out);
    }
}

// Round 10
// 18.305 us; speedup vs baseline: 1.0963x; 1.0963x over previous
//
#include <hip/hip_runtime.h>
#include <hip/hip_bf16.h>
#include <hip/hip_fp16.h>

#define TLEN 4096
#define KTAPS 256
#define NT 18     // Toeplitz A tiles (K window = 288 = 18*16)
#define WCH 32    // B window chunks per block (512 floats)

typedef __attribute__((ext_vector_type(8))) _Float16 f16x8;
typedef __attribute__((ext_vector_type(4))) unsigned int uint4v;
typedef __attribute__((ext_vector_type(16))) float f32x16;

static __device__ __forceinline__ unsigned int pkf16(float a, float b) {
    return __builtin_bit_cast(unsigned int, __builtin_amdgcn_cvt_pkrtz(a, b));
}

// ---------------- Fused kernel: shfl-scan + tap table + LDS Toeplitz MFMA ----------
// Round-6 structure + LDS-transposed coalesced store epilogue.
// Grid: (rows/32) x 16 blocks of 256 threads (4 waves). Block covers rows
// [rt*32,+32) x outputs [sg*256,+256); window t in [sg*256-256, sg*256+256).
__global__ void __launch_bounds__(256, 4)
frac_conv_fused(const float* __restrict__ x,
                const float* __restrict__ loc,
                const float* __restrict__ scale,
                const float* __restrict__ eps,
                float* __restrict__ out) {
    __shared__ __align__(16) float s[KTAPS];                  // 1 KB
    __shared__ unsigned int wrevp[320];                       // 1.25 KB
    __shared__ __align__(16) unsigned short Bf[WCH * 64 * 8]; // 32 KB (reused as Obuf)

    const int tid  = threadIdx.x;
    const int wave = tid >> 6;
    const int lane = tid & 63;
    const int l5   = lane >> 5;
    const int ln   = lane & 31;

    // XCD-aware swizzle: keep the 16 sg-blocks of one row-tile on one XCD.
    int rt, sg;
    if ((gridDim.x & 127) == 0) {
        const int xcd  = blockIdx.x & 7;
        const int slot = blockIdx.x >> 3;
        rt = xcd * 8 + (slot >> 4);
        sg = slot & 15;
    } else {
        rt = blockIdx.x >> 4;
        sg = blockIdx.x & 15;
    }
    const int bn0 = sg * 256;

    // ---- phase 1: burst-issue B window loads (32 rows x 512 floats, coalesced) ----
    const int r  = tid >> 3;          // row 0..31
    const int cg = tid & 7;           // 8 threads/row, 128B contiguous segments
    const float* __restrict__ xrow = x + (size_t)(rt * 32 + r) * TLEN;
    float4 v[16];
    #pragma unroll
    for (int jj = 0; jj < 16; ++jj) {
        const int w0 = cg * 4 + jj * 32;          // float offset in window [0,512)
        const int tg = bn0 - 256 + w0;            // global t of first elem
        v[jj] = (tg >= 0) ? *(const float4*)(xrow + tg) : make_float4(0.f, 0.f, 0.f, 0.f);
    }

    // ---- phase 2: GL coefficient cumprod scan (fp32, LDS) ----
    const float alpha = loc[0] + log1pf(expf(scale[0])) * eps[0];
    {
        const float f = (tid == 0) ? 1.0f : (((float)tid - 1.0f - alpha) / (float)tid);
        s[tid] = f;
        __syncthreads();
        #pragma unroll
        for (int st = 1; st < KTAPS; st <<= 1) {
            const float vv = s[tid];
            const float p  = (tid >= st) ? s[tid - st] : 1.0f;
            __syncthreads();
            s[tid] = vv * p;
            __syncthreads();
        }
    }

    // ---- phase 3: reversed packed fp16 tap table ----
    {
        const int j = tid;
        const float a = (j >= 32) ? s[287 - j] : 0.0f;
        const float b = (j >= 31) ? s[286 - j] : 0.0f;
        wrevp[j] = pkf16(a, b);
        if (tid < 64) {
            const int j2 = 256 + tid;
            const float a2 = (j2 <= 287) ? s[287 - j2] : 0.0f;
            const float b2 = (j2 <= 286) ? s[286 - j2] : 0.0f;
            wrevp[j2] = pkf16(a2, b2);
        }
    }

    // ---- phase 4: convert B to fp16 fragments in LDS ----
    {
        uint2* Bf2 = (uint2*)Bf;
        #pragma unroll
        for (int jj = 0; jj < 16; ++jj) {
            const int w0 = cg * 4 + jj * 32;
            const int c  = w0 >> 4;
            const int h8 = (w0 >> 3) & 1;
            const int e0 = w0 & 7;
            const int uoff = (c * 64 + r + 32 * h8) * 8 + e0;
            Bf2[uoff >> 2] = make_uint2(pkf16(v[jj].x, v[jj].y), pkf16(v[jj].z, v[jj].w));
        }
    }
    __syncthreads();

    // ---- phase 5: MFMA loop; A-fragments on the fly from wrevp ----
    const int n0  = bn0 + wave * 64;
    const int lcb = wave * 4;
    const f16x8* Bv = (const f16x8*)Bf;
    const int o0 = 31 - ln + 8 * l5;

    auto LOADA = [&](int d) -> f16x8 {
        const int o = o0 + 16 * d;
        uint4v u;
        u[0] = wrevp[o];
        u[1] = wrevp[o + 2];
        u[2] = wrevp[o + 4];
        u[3] = wrevp[o + 6];
        return __builtin_bit_cast(f16x8, u);
    };

    f16x8 Afr[NT];
    f16x8 Bfr[NT + 2];
    Bfr[0] = Bv[(lcb + 0) * 64 + lane];
    Bfr[1] = Bv[(lcb + 1) * 64 + lane];
    Bfr[2] = Bv[(lcb + 2) * 64 + lane];
    Bfr[3] = Bv[(lcb + 3) * 64 + lane];
    Afr[0] = LOADA(0);
    Afr[1] = LOADA(1);

    f32x16 acc0 = {0.f, 0.f, 0.f, 0.f, 0.f, 0.f, 0.f, 0.f,
                   0.f, 0.f, 0.f, 0.f, 0.f, 0.f, 0.f, 0.f};
    f32x16 acc1 = acc0;

    #pragma unroll
    for (int d = 0; d < NT; ++d) {
        if (d + 4 < NT + 2) Bfr[d + 4] = Bv[(lcb + d + 4) * 64 + lane];
        if (d + 2 < NT)     Afr[d + 2] = LOADA(d + 2);
        acc0 = __builtin_amdgcn_mfma_f32_32x32x16_f16(Afr[d], Bfr[d],     acc0, 0, 0, 0);
        acc1 = __builtin_amdgcn_mfma_f32_32x32x16_f16(Afr[d], Bfr[d + 2], acc1, 0, 0, 0);
    }

    // ---- epilogue: transpose through LDS, then fully-coalesced row stores ----
    __syncthreads();                      // all waves done reading Bf
    float4* Obuf = (float4*)Bf;           // [32 rows][64 float4 chunks], 32 KB
    {
        // D layout: col = ln (channel row), m = (reg&3) + 8*(reg>>2) + 4*l5.
        // acc0 covers outputs [n0, n0+32), acc1 [n0+32, n0+64).
        const int qb0 = wave * 16;        // float4 chunk base of acc0 span
        const int xr7 = ln & 7;           // XOR swizzle key
        #pragma unroll
        for (int g = 0; g < 4; ++g) {
            const int q0 = qb0 + 2 * g + l5;
            const int q1 = qb0 + 8 + 2 * g + l5;
            Obuf[ln * 64 + (q0 ^ xr7)] =
                make_float4(acc0[4 * g + 0], acc0[4 * g + 1], acc0[4 * g + 2], acc0[4 * g + 3]);
            Obuf[ln * 64 + (q1 ^ xr7)] =
                make_float4(acc1[4 * g + 0], acc1[4 * g + 1], acc1[4 * g + 2], acc1[4 * g + 3]);
        }
    }
    __syncthreads();
    {
        // thread (r = tid>>3, cg = tid&7): store row r, float4 chunks i*8+cg.
        // Per instr: 8 rows x 128 B contiguous per row — full-line writes.
        float* __restrict__ orow2 = out + (size_t)(rt * 32 + r) * TLEN + bn0;
        const int xr7 = r & 7;
        #pragma unroll
        for (int i = 0; i < 8; ++i) {
            const float4 t = Obuf[r * 64 + ((8 * i + cg) ^ xr7)];
            *(float4*)(orow2 + 32 * i + 4 * cg) = t;
        }
    }
}

// ---------------- Fallback path (proven round-1 fp32 kernels) ----------------
__global__ void gl_coeff_kernel(const float* __restrict__ loc,
                                const float* __restrict__ scale,
                                const float* __restrict__ eps,
                                float* __restrict__ w_out) {
    __shared__ float s[KTAPS];
    const int j = threadIdx.x;
    const float alpha = loc[0] + log1pf(expf(scale[0])) * eps[0];
    float f = (j == 0) ? 1.0f : (((float)j - 1.0f - alpha) / (float)j);
    s[j] = f;
    __syncthreads();
    #pragma unroll
    for (int st = 1; st < KTAPS; st <<= 1) {
        float v = s[j];
        float p = (j >= st) ? s[j - st] : 1.0f;
        __syncthreads();
        s[j] = v * p;
        __syncthreads();
    }
    w_out[j] = s[j];
}

__global__ void __launch_bounds__(256)
frac_conv_kernel(const float* __restrict__ x,
                 const float* __restrict__ w,
                 float* __restrict__ out) {
    __shared__ __align__(16) float xs[KTAPS + TLEN];
    __shared__ __align__(16) float wl[KTAPS];
    const int row = blockIdx.x;
    const int tid = threadIdx.x;
    const float* __restrict__ xr = x + (size_t)row * TLEN;
    float* __restrict__ orow = out + (size_t)row * TLEN;
    if (tid < 64) ((float4*)xs)[tid] = make_float4(0.f, 0.f, 0.f, 0.f);
    float4* xs4w = (float4*)(xs + KTAPS);
    const float4* xr4 = (const float4*)xr;
    #pragma unroll
    for (int k = 0; k < 4; ++k) xs4w[tid + k * 256] = xr4[tid + k * 256];
    if (tid < 64) ((float4*)wl)[tid] = ((const float4*)w)[tid];
    __syncthreads();
    const float4* __restrict__ xsv = (const float4*)xs;
    float4 acc[4]; float4 lo[4], hi[4]; int n0[4];
    #pragma unroll
    for (int g = 0; g < 4; ++g) {
        n0[g] = (tid << 2) + (g << 10);
        acc[g] = make_float4(0.f, 0.f, 0.f, 0.f);
        const int c = n0[g] >> 2;
        hi[g] = xsv[64 + c];
        lo[g] = xsv[63 + c];
    }
    #pragma unroll 4
    for (int j = 0; j < KTAPS - 4; j += 4) {
        const float4 w4 = *(const float4*)(wl + j);
        #pragma unroll
        for (int g = 0; g < 4; ++g) {
            acc[g].x += w4.x*hi[g].x + w4.y*lo[g].w + w4.z*lo[g].z + w4.w*lo[g].y;
            acc[g].y += w4.x*hi[g].y + w4.y*hi[g].x + w4.z*lo[g].w + w4.w*lo[g].z;
            acc[g].z += w4.x*hi[g].z + w4.y*hi[g].y + w4.z*hi[g].x + w4.w*lo[g].w;
            acc[g].w += w4.x*hi[g].w + w4.y*hi[g].z + w4.z*hi[g].y + w4.w*hi[g].x;
            hi[g] = lo[g];
            lo[g] = xsv[64 + ((n0[g] - j - 8) >> 2)];
        }
    }
    {
        const float4 w4 = *(const float4*)(wl + (KTAPS - 4));
        #pragma unroll
        for (int g = 0; g < 4; ++g) {
            acc[g].x += w4.x*hi[g].x + w4.y*lo[g].w + w4.z*lo[g].z + w4.w*lo[g].y;
            acc[g].y += w4.x*hi[g].y + w4.y*hi[g].x + w4.z*lo[g].w + w4.w*lo[g].z;
            acc[g].z += w4.x*hi[g].z + w4.y*hi[g].y + w4.z*hi[g].x + w4.w*lo[g].w;
            acc[g].w += w4.x*hi[g].w + w4.y*hi[g].z + w4.z*hi[g].y + w4.w*hi[g].x;
        }
    }
    #pragma unroll
    for (int g = 0; g < 4; ++g) *(float4*)(orow + n0[g]) = acc[g];
}

extern "C" void kernel_launch(void* const* d_in, const int* in_sizes, int n_in,
                              void* d_out, int out_size, void* d_ws, size_t ws_size,
                              hipStream_t stream) {
    const float* x     = (const float*)d_in[0];
    const float* loc   = (const float*)d_in[1];
    const float* scale = (const float*)d_in[2];
    const float* eps   = (const float*)d_in[3];
    float* out = (float*)d_out;
    const int rows = in_sizes[0] / TLEN;  // 2048

    if ((rows % 32) == 0) {
        frac_conv_fused<<<(rows / 32) * 16, 256, 0, stream>>>(x, loc, scale, eps, out);
    } else {
        float* w = (float*)d_ws;
        gl_coeff_kernel<<<1, 256, 0, stream>>>(loc, scale, eps, w);
        frac_conv_kernel<<<rows, 256, 0, stream>>>(x, w, out);
    }
}

// Round 11
// 17.413 us; speedup vs baseline: 1.1525x; 1.0513x over previous
//
#include <hip/hip_runtime.h>
#include <hip/hip_bf16.h>
#include <hip/hip_fp16.h>

#define TLEN 4096
#define KTAPS 256
#define NT 18     // Toeplitz A tiles (K window = 288 = 18*16)
#define WCH 32    // B window chunks per block (512 floats)

typedef __attribute__((ext_vector_type(8))) _Float16 f16x8;
typedef __attribute__((ext_vector_type(4))) unsigned int uint4v;
typedef __attribute__((ext_vector_type(16))) float f32x16;

static __device__ __forceinline__ unsigned int pkf16(float a, float b) {
    return __builtin_bit_cast(unsigned int, __builtin_amdgcn_cvt_pkrtz(a, b));
}

// ---------------- Fused kernel: wave0 shfl-scan + tap table + LDS Toeplitz MFMA ----
// Round-10 structure (256-out/32-row tile, coalesced-store epilogue) with the
// barrier-free wave-0 shfl cumprod scan (ONE barrier before MFMA).
// Grid: (rows/32) x 16 blocks of 256 threads (4 waves). Block covers rows
// [rt*32,+32) x outputs [sg*256,+256); window t in [sg*256-256, sg*256+256).
__global__ void __launch_bounds__(256, 4)
frac_conv_fused(const float* __restrict__ x,
                const float* __restrict__ loc,
                const float* __restrict__ scale,
                const float* __restrict__ eps,
                float* __restrict__ out) {
    __shared__ unsigned int wrevp[320];                       // 1.25 KB
    __shared__ __align__(16) unsigned short Bf[WCH * 64 * 8]; // 32 KB (reused as Obuf)

    const int tid  = threadIdx.x;
    const int wave = tid >> 6;
    const int lane = tid & 63;
    const int l5   = lane >> 5;
    const int ln   = lane & 31;

    // XCD-aware swizzle: keep the 16 sg-blocks of one row-tile on one XCD.
    int rt, sg;
    if ((gridDim.x & 127) == 0) {
        const int xcd  = blockIdx.x & 7;
        const int slot = blockIdx.x >> 3;
        rt = xcd * 8 + (slot >> 4);
        sg = slot & 15;
    } else {
        rt = blockIdx.x >> 4;
        sg = blockIdx.x & 15;
    }
    const int bn0 = sg * 256;

    // ---- phase 1: burst-issue B window loads (32 rows x 512 floats, coalesced) ----
    const int r  = tid >> 3;          // row 0..31
    const int cg = tid & 7;           // 8 threads/row, 128B contiguous segments
    const float* __restrict__ xrow = x + (size_t)(rt * 32 + r) * TLEN;
    float4 v[16];
    #pragma unroll
    for (int jj = 0; jj < 16; ++jj) {
        const int w0 = cg * 4 + jj * 32;          // float offset in window [0,512)
        const int tg = bn0 - 256 + w0;            // global t of first elem
        v[jj] = (tg >= 0) ? *(const float4*)(xrow + tg) : make_float4(0.f, 0.f, 0.f, 0.f);
    }

    // ---- phase 2: wave 0 shfl cumprod scan -> packed reversed fp16 tap table ----
    // w_0=1, w_j = w_{j-1}*(j-1-alpha)/j. Lane l holds w[4l..4l+3] (+ w[4l-1]).
    // wrevp[j] = pack(wrev[j], wrev[j+1]), wrev[j] = w[287-j] (0 outside [0,255]).
    if (wave == 0) {
        const float alpha = loc[0] + log1pf(expf(scale[0])) * eps[0];
        const int j0 = 4 * lane;
        const float f0 = (j0 == 0) ? 1.0f : (((float)j0 - 1.0f - alpha) / (float)j0);
        const float f1 = (((float)j0 + 0.0f - alpha) / (float)(j0 + 1));
        const float f2 = (((float)j0 + 1.0f - alpha) / (float)(j0 + 2));
        const float f3 = (((float)j0 + 2.0f - alpha) / (float)(j0 + 3));
        const float p0 = f0, p1 = p0 * f1, p2 = p1 * f2, p3 = p2 * f3;
        float g = p3;
        #pragma unroll
        for (int dlt = 1; dlt < 64; dlt <<= 1) {
            const float t = __shfl_up(g, dlt, 64);
            if (lane >= dlt) g *= t;
        }
        float Sprev = __shfl_up(g, 1, 64);
        if (lane == 0) Sprev = 1.0f;
        const float q0 = Sprev * p0, q1 = Sprev * p1, q2 = Sprev * p2, q3 = g;
        const float wm1 = (lane == 0) ? 0.0f : Sprev;   // w[4l-1]
        // 4 packed words at 284-4*lane: (q3,q2),(q2,q1),(q1,q0),(q0,wm1)
        uint4v pk;
        pk[0] = pkf16(q3, q2);
        pk[1] = pkf16(q2, q1);
        pk[2] = pkf16(q1, q0);
        pk[3] = pkf16(q0, wm1);
        *(uint4v*)(wrevp + 284 - 4 * lane) = pk;        // 16B aligned
        if (lane == 63) wrevp[31] = pkf16(0.0f, q3);    // pack(w[256]=0, w[255])
        if (lane < 31)  wrevp[lane] = 0u;               // wrev[j]=0, j<31
        if (lane < 32)  wrevp[288 + lane] = 0u;         // wrev[j]=0, j>=288
    }

    // ---- phase 3: convert B to fp16 fragments in LDS (waits loads on demand) ----
    {
        uint2* Bf2 = (uint2*)Bf;
        #pragma unroll
        for (int jj = 0; jj < 16; ++jj) {
            const int w0 = cg * 4 + jj * 32;
            const int c  = w0 >> 4;
            const int h8 = (w0 >> 3) & 1;
            const int e0 = w0 & 7;
            const int uoff = (c * 64 + r + 32 * h8) * 8 + e0;
            Bf2[uoff >> 2] = make_uint2(pkf16(v[jj].x, v[jj].y), pkf16(v[jj].z, v[jj].w));
        }
    }
    __syncthreads();   // the ONLY barrier before MFMA

    // ---- phase 4: MFMA loop; A-fragments on the fly from wrevp ----
    const int n0  = bn0 + wave * 64;
    const int lcb = wave * 4;
    const f16x8* Bv = (const f16x8*)Bf;
    const int o0 = 31 - ln + 8 * l5;

    auto LOADA = [&](int d) -> f16x8 {
        const int o = o0 + 16 * d;
        uint4v u;
        u[0] = wrevp[o];
        u[1] = wrevp[o + 2];
        u[2] = wrevp[o + 4];
        u[3] = wrevp[o + 6];
        return __builtin_bit_cast(f16x8, u);
    };

    f16x8 Afr[NT];
    f16x8 Bfr[NT + 2];
    Bfr[0] = Bv[(lcb + 0) * 64 + lane];
    Bfr[1] = Bv[(lcb + 1) * 64 + lane];
    Bfr[2] = Bv[(lcb + 2) * 64 + lane];
    Bfr[3] = Bv[(lcb + 3) * 64 + lane];
    Afr[0] = LOADA(0);
    Afr[1] = LOADA(1);

    f32x16 acc0 = {0.f, 0.f, 0.f, 0.f, 0.f, 0.f, 0.f, 0.f,
                   0.f, 0.f, 0.f, 0.f, 0.f, 0.f, 0.f, 0.f};
    f32x16 acc1 = acc0;

    #pragma unroll
    for (int d = 0; d < NT; ++d) {
        if (d + 4 < NT + 2) Bfr[d + 4] = Bv[(lcb + d + 4) * 64 + lane];
        if (d + 2 < NT)     Afr[d + 2] = LOADA(d + 2);
        acc0 = __builtin_amdgcn_mfma_f32_32x32x16_f16(Afr[d], Bfr[d],     acc0, 0, 0, 0);
        acc1 = __builtin_amdgcn_mfma_f32_32x32x16_f16(Afr[d], Bfr[d + 2], acc1, 0, 0, 0);
    }

    // ---- epilogue: transpose through LDS, then fully-coalesced row stores ----
    __syncthreads();                      // all waves done reading Bf
    float4* Obuf = (float4*)Bf;           // [32 rows][64 float4 chunks], 32 KB
    {
        // D layout: col = ln (channel row), m = (reg&3) + 8*(reg>>2) + 4*l5.
        const int qb0 = wave * 16;        // float4 chunk base of acc0 span
        const int xr7 = ln & 7;           // XOR swizzle key
        #pragma unroll
        for (int g = 0; g < 4; ++g) {
            const int q0 = qb0 + 2 * g + l5;
            const int q1 = qb0 + 8 + 2 * g + l5;
            Obuf[ln * 64 + (q0 ^ xr7)] =
                make_float4(acc0[4 * g + 0], acc0[4 * g + 1], acc0[4 * g + 2], acc0[4 * g + 3]);
            Obuf[ln * 64 + (q1 ^ xr7)] =
                make_float4(acc1[4 * g + 0], acc1[4 * g + 1], acc1[4 * g + 2], acc1[4 * g + 3]);
        }
    }
    __syncthreads();
    {
        // thread (r, cg): store row r, float4 chunks i*8+cg — 128B contiguous/row.
        float* __restrict__ orow2 = out + (size_t)(rt * 32 + r) * TLEN + bn0;
        const int xr7 = r & 7;
        #pragma unroll
        for (int i = 0; i < 8; ++i) {
            const float4 t = Obuf[r * 64 + ((8 * i + cg) ^ xr7)];
            *(float4*)(orow2 + 32 * i + 4 * cg) = t;
        }
    }
}

// ---------------- Fallback path (proven round-1 fp32 kernels) ----------------
__global__ void gl_coeff_kernel(const float* __restrict__ loc,
                                const float* __restrict__ scale,
                                const float* __restrict__ eps,
                                float* __restrict__ w_out) {
    __shared__ float s[KTAPS];
    const int j = threadIdx.x;
    const float alpha = loc[0] + log1pf(expf(scale[0])) * eps[0];
    float f = (j == 0) ? 1.0f : (((float)j - 1.0f - alpha) / (float)j);
    s[j] = f;
    __syncthreads();
    #pragma unroll
    for (int st = 1; st < KTAPS; st <<= 1) {
        float v = s[j];
        float p = (j >= st) ? s[j - st] : 1.0f;
        __syncthreads();
        s[j] = v * p;
        __syncthreads();
    }
    w_out[j] = s[j];
}

__global__ void __launch_bounds__(256)
frac_conv_kernel(const float* __restrict__ x,
                 const float* __restrict__ w,
                 float* __restrict__ out) {
    __shared__ __align__(16) float xs[KTAPS + TLEN];
    __shared__ __align__(16) float wl[KTAPS];
    const int row = blockIdx.x;
    const int tid = threadIdx.x;
    const float* __restrict__ xr = x + (size_t)row * TLEN;
    float* __restrict__ orow = out + (size_t)row * TLEN;
    if (tid < 64) ((float4*)xs)[tid] = make_float4(0.f, 0.f, 0.f, 0.f);
    float4* xs4w = (float4*)(xs + KTAPS);
    const float4* xr4 = (const float4*)xr;
    #pragma unroll
    for (int k = 0; k < 4; ++k) xs4w[tid + k * 256] = xr4[tid + k * 256];
    if (tid < 64) ((float4*)wl)[tid] = ((const float4*)w)[tid];
    __syncthreads();
    const float4* __restrict__ xsv = (const float4*)xs;
    float4 acc[4]; float4 lo[4], hi[4]; int n0[4];
    #pragma unroll
    for (int g = 0; g < 4; ++g) {
        n0[g] = (tid << 2) + (g << 10);
        acc[g] = make_float4(0.f, 0.f, 0.f, 0.f);
        const int c = n0[g] >> 2;
        hi[g] = xsv[64 + c];
        lo[g] = xsv[63 + c];
    }
    #pragma unroll 4
    for (int j = 0; j < KTAPS - 4; j += 4) {
        const float4 w4 = *(const float4*)(wl + j);
        #pragma unroll
        for (int g = 0; g < 4; ++g) {
            acc[g].x += w4.x*hi[g].x + w4.y*lo[g].w + w4.z*lo[g].z + w4.w*lo[g].y;
            acc[g].y += w4.x*hi[g].y + w4.y*hi[g].x + w4.z*lo[g].w + w4.w*lo[g].z;
            acc[g].z += w4.x*hi[g].z + w4.y*hi[g].y + w4.z*hi[g].x + w4.w*lo[g].w;
            acc[g].w += w4.x*hi[g].w + w4.y*hi[g].z + w4.z*hi[g].y + w4.w*hi[g].x;
            hi[g] = lo[g];
            lo[g] = xsv[64 + ((n0[g] - j - 8) >> 2)];
        }
    }
    {
        const float4 w4 = *(const float4*)(wl + (KTAPS - 4));
        #pragma unroll
        for (int g = 0; g < 4; ++g) {
            acc[g].x += w4.x*hi[g].x + w4.y*lo[g].w + w4.z*lo[g].z + w4.w*lo[g].y;
            acc[g].y += w4.x*hi[g].y + w4.y*hi[g].x + w4.z*lo[g].w + w4.w*lo[g].z;
            acc[g].z += w4.x*hi[g].z + w4.y*hi[g].y + w4.z*hi[g].x + w4.w*lo[g].w;
            acc[g].w += w4.x*hi[g].w + w4.y*hi[g].z + w4.z*hi[g].y + w4.w*hi[g].x;
        }
    }
    #pragma unroll
    for (int g = 0; g < 4; ++g) *(float4*)(orow + n0[g]) = acc[g];
}

extern "C" void kernel_launch(void* const* d_in, const int* in_sizes, int n_in,
                              void* d_out, int out_size, void* d_ws, size_t ws_size,
                              hipStream_t stream) {
    const float* x     = (const float*)d_in[0];
    const float* loc   = (const float*)d_in[1];
    const float* scale = (const float*)d_in[2];
    const float* eps   = (const float*)d_in[3];
    float* out = (float*)d_out;
    const int rows = in_sizes[0] / TLEN;  // 2048

    if ((rows % 32) == 0) {
        frac_conv_fused<<<(rows / 32) * 16, 256, 0, stream>>>(x, loc, scale, eps, out);
    } else {
        float* w = (float*)d_ws;
        gl_coeff_kernel<<<1, 256, 0, stream>>>(loc, scale, eps, w);
        frac_conv_kernel<<<rows, 256, 0, stream>>>(x, w, out);
    }
}

// Round 12
// 17.273 us; speedup vs baseline: 1.1618x; 1.0081x over previous
//
#include <hip/hip_runtime.h>
#include <hip/hip_bf16.h>
#include <hip/hip_fp16.h>

#define TLEN 4096
#define KTAPS 256
#define NT 18     // Toeplitz A tiles (K window = 288 = 18*16)
#define WCH 32    // B window chunks per block (512 floats)

typedef __attribute__((ext_vector_type(8))) _Float16 f16x8;
typedef __attribute__((ext_vector_type(4))) unsigned int uint4v;
typedef __attribute__((ext_vector_type(16))) float f32x16;

static __device__ __forceinline__ unsigned int pkf16(float a, float b) {
    return __builtin_bit_cast(unsigned int, __builtin_amdgcn_cvt_pkrtz(a, b));
}

// ---------------- Fused kernel: wave0 shfl-scan + tap table + LDS Toeplitz MFMA ----
// Round-11 structure; loads issued main-half-first / halo-last so the halo fetch
// (shared with the sg-1 neighbor block) hits L2 instead of duplicating HBM reads.
// Grid: (rows/32) x 16 blocks of 256 threads (4 waves). Block covers rows
// [rt*32,+32) x outputs [sg*256,+256); window t in [sg*256-256, sg*256+256).
__global__ void __launch_bounds__(256, 4)
frac_conv_fused(const float* __restrict__ x,
                const float* __restrict__ loc,
                const float* __restrict__ scale,
                const float* __restrict__ eps,
                float* __restrict__ out) {
    __shared__ unsigned int wrevp[320];                       // 1.25 KB
    __shared__ __align__(16) unsigned short Bf[WCH * 64 * 8]; // 32 KB (reused as Obuf)

    const int tid  = threadIdx.x;
    const int wave = tid >> 6;
    const int lane = tid & 63;
    const int l5   = lane >> 5;
    const int ln   = lane & 31;

    // XCD-aware swizzle: keep the 16 sg-blocks of one row-tile on one XCD.
    int rt, sg;
    if ((gridDim.x & 127) == 0) {
        const int xcd  = blockIdx.x & 7;
        const int slot = blockIdx.x >> 3;
        rt = xcd * 8 + (slot >> 4);
        sg = slot & 15;
    } else {
        rt = blockIdx.x >> 4;
        sg = blockIdx.x & 15;
    }
    const int bn0 = sg * 256;

    // ---- phase 1: burst-issue B window loads, MAIN half (jj 8..15) first, halo last --
    const int r  = tid >> 3;          // row 0..31
    const int cg = tid & 7;           // 8 threads/row, 128B contiguous segments
    const float* __restrict__ xrow = x + (size_t)(rt * 32 + r) * TLEN;
    float4 v[16];
    #pragma unroll
    for (int q = 0; q < 16; ++q) {
        const int jj = (q + 8) & 15;              // 8..15 then 0..7
        const int w0 = cg * 4 + jj * 32;          // float offset in window [0,512)
        const int tg = bn0 - 256 + w0;            // global t of first elem
        v[jj] = (tg >= 0) ? *(const float4*)(xrow + tg) : make_float4(0.f, 0.f, 0.f, 0.f);
    }

    // ---- phase 2: wave 0 shfl cumprod scan -> packed reversed fp16 tap table ----
    // w_0=1, w_j = w_{j-1}*(j-1-alpha)/j. Lane l holds w[4l..4l+3] (+ w[4l-1]).
    // wrevp[j] = pack(wrev[j], wrev[j+1]), wrev[j] = w[287-j] (0 outside [0,255]).
    if (wave == 0) {
        const float alpha = loc[0] + log1pf(expf(scale[0])) * eps[0];
        const int j0 = 4 * lane;
        const float f0 = (j0 == 0) ? 1.0f : (((float)j0 - 1.0f - alpha) / (float)j0);
        const float f1 = (((float)j0 + 0.0f - alpha) / (float)(j0 + 1));
        const float f2 = (((float)j0 + 1.0f - alpha) / (float)(j0 + 2));
        const float f3 = (((float)j0 + 2.0f - alpha) / (float)(j0 + 3));
        const float p0 = f0, p1 = p0 * f1, p2 = p1 * f2, p3 = p2 * f3;
        float g = p3;
        #pragma unroll
        for (int dlt = 1; dlt < 64; dlt <<= 1) {
            const float t = __shfl_up(g, dlt, 64);
            if (lane >= dlt) g *= t;
        }
        float Sprev = __shfl_up(g, 1, 64);
        if (lane == 0) Sprev = 1.0f;
        const float q0 = Sprev * p0, q1 = Sprev * p1, q2 = Sprev * p2, q3 = g;
        const float wm1 = (lane == 0) ? 0.0f : Sprev;   // w[4l-1]
        // 4 packed words at 284-4*lane: (q3,q2),(q2,q1),(q1,q0),(q0,wm1)
        uint4v pk;
        pk[0] = pkf16(q3, q2);
        pk[1] = pkf16(q2, q1);
        pk[2] = pkf16(q1, q0);
        pk[3] = pkf16(q0, wm1);
        *(uint4v*)(wrevp + 284 - 4 * lane) = pk;        // 16B aligned
        if (lane == 63) wrevp[31] = pkf16(0.0f, q3);    // pack(w[256]=0, w[255])
        if (lane < 31)  wrevp[lane] = 0u;               // wrev[j]=0, j<31
        if (lane < 32)  wrevp[288 + lane] = 0u;         // wrev[j]=0, j>=288
    }

    // ---- phase 3: convert B to fp16 fragments in LDS (same order as issue) ----
    {
        uint2* Bf2 = (uint2*)Bf;
        #pragma unroll
        for (int q = 0; q < 16; ++q) {
            const int jj = (q + 8) & 15;
            const int w0 = cg * 4 + jj * 32;
            const int c  = w0 >> 4;
            const int h8 = (w0 >> 3) & 1;
            const int e0 = w0 & 7;
            const int uoff = (c * 64 + r + 32 * h8) * 8 + e0;
            Bf2[uoff >> 2] = make_uint2(pkf16(v[jj].x, v[jj].y), pkf16(v[jj].z, v[jj].w));
        }
    }
    __syncthreads();   // the ONLY barrier before MFMA

    // ---- phase 4: MFMA loop; A-fragments on the fly from wrevp ----
    const int n0  = bn0 + wave * 64;
    const int lcb = wave * 4;
    const f16x8* Bv = (const f16x8*)Bf;
    const int o0 = 31 - ln + 8 * l5;

    auto LOADA = [&](int d) -> f16x8 {
        const int o = o0 + 16 * d;
        uint4v u;
        u[0] = wrevp[o];
        u[1] = wrevp[o + 2];
        u[2] = wrevp[o + 4];
        u[3] = wrevp[o + 6];
        return __builtin_bit_cast(f16x8, u);
    };

    f16x8 Afr[NT];
    f16x8 Bfr[NT + 2];
    Bfr[0] = Bv[(lcb + 0) * 64 + lane];
    Bfr[1] = Bv[(lcb + 1) * 64 + lane];
    Bfr[2] = Bv[(lcb + 2) * 64 + lane];
    Bfr[3] = Bv[(lcb + 3) * 64 + lane];
    Afr[0] = LOADA(0);
    Afr[1] = LOADA(1);

    f32x16 acc0 = {0.f, 0.f, 0.f, 0.f, 0.f, 0.f, 0.f, 0.f,
                   0.f, 0.f, 0.f, 0.f, 0.f, 0.f, 0.f, 0.f};
    f32x16 acc1 = acc0;

    #pragma unroll
    for (int d = 0; d < NT; ++d) {
        if (d + 4 < NT + 2) Bfr[d + 4] = Bv[(lcb + d + 4) * 64 + lane];
        if (d + 2 < NT)     Afr[d + 2] = LOADA(d + 2);
        acc0 = __builtin_amdgcn_mfma_f32_32x32x16_f16(Afr[d], Bfr[d],     acc0, 0, 0, 0);
        acc1 = __builtin_amdgcn_mfma_f32_32x32x16_f16(Afr[d], Bfr[d + 2], acc1, 0, 0, 0);
    }

    // ---- epilogue: transpose through LDS, then fully-coalesced row stores ----
    __syncthreads();                      // all waves done reading Bf
    float4* Obuf = (float4*)Bf;           // [32 rows][64 float4 chunks], 32 KB
    {
        // D layout: col = ln (channel row), m = (reg&3) + 8*(reg>>2) + 4*l5.
        const int qb0 = wave * 16;        // float4 chunk base of acc0 span
        const int xr7 = ln & 7;           // XOR swizzle key
        #pragma unroll
        for (int g = 0; g < 4; ++g) {
            const int q0 = qb0 + 2 * g + l5;
            const int q1 = qb0 + 8 + 2 * g + l5;
            Obuf[ln * 64 + (q0 ^ xr7)] =
                make_float4(acc0[4 * g + 0], acc0[4 * g + 1], acc0[4 * g + 2], acc0[4 * g + 3]);
            Obuf[ln * 64 + (q1 ^ xr7)] =
                make_float4(acc1[4 * g + 0], acc1[4 * g + 1], acc1[4 * g + 2], acc1[4 * g + 3]);
        }
    }
    __syncthreads();
    {
        // thread (r, cg): store row r, float4 chunks i*8+cg — 128B contiguous/row.
        float* __restrict__ orow2 = out + (size_t)(rt * 32 + r) * TLEN + bn0;
        const int xr7 = r & 7;
        #pragma unroll
        for (int i = 0; i < 8; ++i) {
            const float4 t = Obuf[r * 64 + ((8 * i + cg) ^ xr7)];
            *(float4*)(orow2 + 32 * i + 4 * cg) = t;
        }
    }
}

// ---------------- Fallback path (proven round-1 fp32 kernels) ----------------
__global__ void gl_coeff_kernel(const float* __restrict__ loc,
                                const float* __restrict__ scale,
                                const float* __restrict__ eps,
                                float* __restrict__ w_out) {
    __shared__ float s[KTAPS];
    const int j = threadIdx.x;
    const float alpha = loc[0] + log1pf(expf(scale[0])) * eps[0];
    float f = (j == 0) ? 1.0f : (((float)j - 1.0f - alpha) / (float)j);
    s[j] = f;
    __syncthreads();
    #pragma unroll
    for (int st = 1; st < KTAPS; st <<= 1) {
        float v = s[j];
        float p = (j >= st) ? s[j - st] : 1.0f;
        __syncthreads();
        s[j] = v * p;
        __syncthreads();
    }
    w_out[j] = s[j];
}

__global__ void __launch_bounds__(256)
frac_conv_kernel(const float* __restrict__ x,
                 const float* __restrict__ w,
                 float* __restrict__ out) {
    __shared__ __align__(16) float xs[KTAPS + TLEN];
    __shared__ __align__(16) float wl[KTAPS];
    const int row = blockIdx.x;
    const int tid = threadIdx.x;
    const float* __restrict__ xr = x + (size_t)row * TLEN;
    float* __restrict__ orow = out + (size_t)row * TLEN;
    if (tid < 64) ((float4*)xs)[tid] = make_float4(0.f, 0.f, 0.f, 0.f);
    float4* xs4w = (float4*)(xs + KTAPS);
    const float4* xr4 = (const float4*)xr;
    #pragma unroll
    for (int k = 0; k < 4; ++k) xs4w[tid + k * 256] = xr4[tid + k * 256];
    if (tid < 64) ((float4*)wl)[tid] = ((const float4*)w)[tid];
    __syncthreads();
    const float4* __restrict__ xsv = (const float4*)xs;
    float4 acc[4]; float4 lo[4], hi[4]; int n0[4];
    #pragma unroll
    for (int g = 0; g < 4; ++g) {
        n0[g] = (tid << 2) + (g << 10);
        acc[g] = make_float4(0.f, 0.f, 0.f, 0.f);
        const int c = n0[g] >> 2;
        hi[g] = xsv[64 + c];
        lo[g] = xsv[63 + c];
    }
    #pragma unroll 4
    for (int j = 0; j < KTAPS - 4; j += 4) {
        const float4 w4 = *(const float4*)(wl + j);
        #pragma unroll
        for (int g = 0; g < 4; ++g) {
            acc[g].x += w4.x*hi[g].x + w4.y*lo[g].w + w4.z*lo[g].z + w4.w*lo[g].y;
            acc[g].y += w4.x*hi[g].y + w4.y*hi[g].x + w4.z*lo[g].w + w4.w*lo[g].z;
            acc[g].z += w4.x*hi[g].z + w4.y*hi[g].y + w4.z*hi[g].x + w4.w*lo[g].w;
            acc[g].w += w4.x*hi[g].w + w4.y*hi[g].z + w4.z*hi[g].y + w4.w*hi[g].x;
            hi[g] = lo[g];
            lo[g] = xsv[64 + ((n0[g] - j - 8) >> 2)];
        }
    }
    {
        const float4 w4 = *(const float4*)(wl + (KTAPS - 4));
        #pragma unroll
        for (int g = 0; g < 4; ++g) {
            acc[g].x += w4.x*hi[g].x + w4.y*lo[g].w + w4.z*lo[g].z + w4.w*lo[g].y;
            acc[g].y += w4.x*hi[g].y + w4.y*hi[g].x + w4.z*lo[g].w + w4.w*lo[g].z;
            acc[g].z += w4.x*hi[g].z + w4.y*hi[g].y + w4.z*hi[g].x + w4.w*lo[g].w;
            acc[g].w += w4.x*hi[g].w + w4.y*hi[g].z + w4.z*hi[g].y + w4.w*hi[g].x;
        }
    }
    #pragma unroll
    for (int g = 0; g < 4; ++g) *(float4*)(orow + n0[g]) = acc[g];
}

extern "C" void kernel_launch(void* const* d_in, const int* in_sizes, int n_in,
                              void* d_out, int out_size, void* d_ws, size_t ws_size,
                              hipStream_t stream) {
    const float* x     = (const float*)d_in[0];
    const float* loc   = (const float*)d_in[1];
    const float* scale = (const float*)d_in[2];
    const float* eps   = (const float*)d_in[3];
    float* out = (float*)d_out;
    const int rows = in_sizes[0] / TLEN;  // 2048

    if ((rows % 32) == 0) {
        frac_conv_fused<<<(rows / 32) * 16, 256, 0, stream>>>(x, loc, scale, eps, out);
    } else {
        float* w = (float*)d_ws;
        gl_coeff_kernel<<<1, 256, 0, stream>>>(loc, scale, eps, w);
        frac_conv_kernel<<<rows, 256, 0, stream>>>(x, w, out);
    }
}